// Round 5
// baseline (202.731 us; speedup 1.0000x reference)
//
#include <hip/hip_runtime.h>
#include <math.h>

#define NB 16
#define NL 1024
#define NH 8
#define NE 64
#define NWIN 1024
#define NG 64

#define SCH 128     // s-chunk per block in k_attn_out
#define SROW 136    // sb row stride in shorts (136*2=272 B, 16B-aligned)

typedef __attribute__((ext_vector_type(8))) short short8;
typedef __attribute__((ext_vector_type(4))) float floatx4;

__device__ __forceinline__ short f2bf(float x) {
    unsigned u = __float_as_uint(x);
    u += 0x7fffu + ((u >> 16) & 1u);   // round-to-nearest-even
    return (short)(u >> 16);
}
__device__ __forceinline__ float dot4(float4 a, float4 b) {
    return fmaf(a.x, b.x, fmaf(a.y, b.y, fmaf(a.z, b.z, a.w * b.w)));
}

// Fused tanh-MLP + qp/qn. Block = (b, h, eighth qq of the l-range), 1024
// blocks. Wave owns 4 rows; x loads double-buffered across rows; 8-output
// cross-lane reduction via merge-tree (17 shfl + 7 cndmask vs 48 shfl).
// t stays wave-private in LDS (no barrier between phase 1 and 2).
__global__ __launch_bounds__(256) void k_sel_q(
    const float* __restrict__ x, const float* __restrict__ mlp_w,
    const float* __restrict__ mlp_b, const float* __restrict__ q,
    float* __restrict__ qp, float* __restrict__ qn)
{
    __shared__ float4 w_lds[8][NWIN / 4];   // 32 KB
    __shared__ float t_lds[128];
    __shared__ float redp[4][64], redn[4][64];

    int tid = threadIdx.x;
    int blk = blockIdx.x;
    int qq = blk & 7, bh = blk >> 3;
    int b = bh >> 3, h = bh & 7;
    int w = tid >> 6, lane = tid & 63;

    const float4* w4 = (const float4*)mlp_w;
    float4* wl = (float4*)w_lds;
    #pragma unroll
    for (int i = 0; i < 8; ++i)
        wl[tid + 256 * i] = w4[tid + 256 * i];
    __syncthreads();

    // ---- phase 1: tanh-MLP, 4 rows per wave, double-buffered x ----
    int r0 = b * 1024 + h * 128 + qq * 16 + w * 4;
    float bc = mlp_b[lane & 7];
    float4 xa[4], xb[4];
    {
        const float4* p0 = (const float4*)(x + (size_t)r0 * NWIN);
        #pragma unroll
        for (int it = 0; it < 4; ++it) xa[it] = p0[it * 64 + lane];
    }
    #pragma unroll
    for (int j = 0; j < 4; ++j) {
        if (j < 3) {
            const float4* pn = (const float4*)(x + (size_t)(r0 + j + 1) * NWIN);
            #pragma unroll
            for (int it = 0; it < 4; ++it) xb[it] = pn[it * 64 + lane];
        }
        float o0=0,o1=0,o2=0,o3=0,o4=0,o5=0,o6=0,o7=0;
        #pragma unroll
        for (int it = 0; it < 4; ++it) {
            float4 xv = xa[it];
            o0 += dot4(xv, w_lds[0][it * 64 + lane]);
            o1 += dot4(xv, w_lds[1][it * 64 + lane]);
            o2 += dot4(xv, w_lds[2][it * 64 + lane]);
            o3 += dot4(xv, w_lds[3][it * 64 + lane]);
            o4 += dot4(xv, w_lds[4][it * 64 + lane]);
            o5 += dot4(xv, w_lds[5][it * 64 + lane]);
            o6 += dot4(xv, w_lds[6][it * 64 + lane]);
            o7 += dot4(xv, w_lds[7][it * 64 + lane]);
        }
        // merge-tree reduction: lane ends with full sum of output c=lane&7
        o0 += __shfl_xor(o0, 1, 64); o1 += __shfl_xor(o1, 1, 64);
        o2 += __shfl_xor(o2, 1, 64); o3 += __shfl_xor(o3, 1, 64);
        o4 += __shfl_xor(o4, 1, 64); o5 += __shfl_xor(o5, 1, 64);
        o6 += __shfl_xor(o6, 1, 64); o7 += __shfl_xor(o7, 1, 64);
        bool b0 = lane & 1;
        float m0 = b0 ? o1 : o0, m1 = b0 ? o3 : o2;
        float m2 = b0 ? o5 : o4, m3 = b0 ? o7 : o6;
        m0 += __shfl_xor(m0, 2, 64); m1 += __shfl_xor(m1, 2, 64);
        m2 += __shfl_xor(m2, 2, 64); m3 += __shfl_xor(m3, 2, 64);
        bool b1 = lane & 2;
        float n0 = b1 ? m1 : m0, n1 = b1 ? m3 : m2;
        n0 += __shfl_xor(n0, 4, 64); n1 += __shfl_xor(n1, 4, 64);
        float q0 = (lane & 4) ? n1 : n0;
        q0 += __shfl_xor(q0, 8, 64);
        q0 += __shfl_xor(q0, 16, 64);
        q0 += __shfl_xor(q0, 32, 64);
        if (lane < 8)
            t_lds[w * 32 + j * 8 + lane] = tanhf(q0 + bc);
        #pragma unroll
        for (int it = 0; it < 4; ++it) xa[it] = xb[it];
    }
    // no barrier: wave w only reads t_lds[w*32 .. w*32+32)

    // ---- phase 2: qp/qn partial over l in [qq*128, qq*128+128) ----
    int lo = lane >> 4, e4 = lane & 15;
    float4 accp = make_float4(0,0,0,0), accn = make_float4(0,0,0,0);
    #pragma unroll
    for (int i = 0; i < 8; ++i) {
        int l_loc = w * 32 + i * 4 + lo;
        float tv = t_lds[l_loc];
        int l = qq * 128 + l_loc;
        float4 qv = *(const float4*)(q + (((size_t)(b * NL + l)) * NH + h) * NE + e4 * 4);
        float tp = fmaxf(tv, 0.f), tn = fminf(tv, 0.f);
        accp.x = fmaf(tp, qv.x, accp.x); accp.y = fmaf(tp, qv.y, accp.y);
        accp.z = fmaf(tp, qv.z, accp.z); accp.w = fmaf(tp, qv.w, accp.w);
        accn.x = fmaf(tn, qv.x, accn.x); accn.y = fmaf(tn, qv.y, accn.y);
        accn.z = fmaf(tn, qv.z, accn.z); accn.w = fmaf(tn, qv.w, accn.w);
    }
    #pragma unroll
    for (int off = 16; off <= 32; off <<= 1) {
        accp.x += __shfl_xor(accp.x, off, 64); accp.y += __shfl_xor(accp.y, off, 64);
        accp.z += __shfl_xor(accp.z, off, 64); accp.w += __shfl_xor(accp.w, off, 64);
        accn.x += __shfl_xor(accn.x, off, 64); accn.y += __shfl_xor(accn.y, off, 64);
        accn.z += __shfl_xor(accn.z, off, 64); accn.w += __shfl_xor(accn.w, off, 64);
    }
    if (lo == 0) {
        *(float4*)&redp[w][e4 * 4] = accp;
        *(float4*)&redn[w][e4 * 4] = accn;
    }
    __syncthreads();
    if (tid < 64) {
        atomicAdd(&qp[bh * NE + tid], redp[0][tid] + redp[1][tid] + redp[2][tid] + redp[3][tid]);
    } else if (tid < 128) {
        int e = tid - 64;
        atomicAdd(&qn[bh * NE + e], redn[0][e] + redn[1][e] + redn[2][e] + redn[3][e]);
    }
}

// Attention v5: per (b, h, s-chunk of 128). v gathered into registers FIRST
// (in flight across phases A/B barriers), bf16 pack at MFMA time. Epilogue:
// plain coalesced stores of per-chunk partials into ws [chunk][out_flat]
// (round-4's 4M global atomics eliminated).
__global__ __launch_bounds__(256, 4) void k_attn_out(
    const float* __restrict__ keys, const float* __restrict__ values,
    const float* __restrict__ sel_W,
    const float* __restrict__ qp, const float* __restrict__ qn,
    float* __restrict__ partial)
{
    __shared__ short sb[NG][SROW];          // 17 KB  series bf16, [g][s]
    __shared__ float ap_l[SCH], an_l[SCH];
    __shared__ float2 wpn[NG];
    __shared__ float mx2[2][SCH], dn2[2][SCH];

    int tid = threadIdx.x, blk = blockIdx.x;
    int chunk = blk & 7, bh = blk >> 3;
    int b = bh >> 3, h = bh & 7;
    int w = tid >> 6, lane = tid & 63;
    int c = lane & 15, sq = lane >> 4;
    const float scale = 0.125f;             // 1/sqrt(64)
    int s0 = chunk * SCH;

    // ---- v prefetch: 32 scalar f32, in flight through phases A/B ----
    float vreg[32];
    const float* vbase = values + (((size_t)(b * NL + s0)) * NH + h) * NE + 16 * w + c;
    #pragma unroll
    for (int ks = 0; ks < 4; ++ks)
        #pragma unroll
        for (int j = 0; j < 8; ++j)
            vreg[ks * 8 + j] = vbase[(size_t)(ks * 32 + sq * 8 + j) * (NH * NE)];

    if (tid < NG) {
        float W = sel_W[h * NG + tid];
        wpn[tid] = make_float2(fmaxf(W, 0.f) * scale, fminf(W, 0.f) * scale);
    }
    const float4 qp4 = *(const float4*)(qp + bh * NE + c * 4);
    const float4 qn4 = *(const float4*)(qn + bh * NE + c * 4);

    // ---- phase A: ap/an (wave owns 32 s) ----
    #pragma unroll
    for (int p = 0; p < 8; ++p) {
        int sl = w * 32 + p * 4 + sq;
        float4 kv = *(const float4*)(keys + (((size_t)(b * NL + s0 + sl)) * NH + h) * NE + c * 4);
        float pp = dot4(kv, qp4);
        float pn = dot4(kv, qn4);
        #pragma unroll
        for (int m_ = 1; m_ <= 8; m_ <<= 1) {
            pp += __shfl_xor(pp, m_, 64);
            pn += __shfl_xor(pn, m_, 64);
        }
        if (c == 0) { ap_l[sl] = pp; an_l[sl] = pn; }
    }
    __syncthreads();

    // ---- phase B: softmax over g, g-range split across thread halves ----
    {
        int s_ = tid & 127, gh = tid >> 7, g0 = gh * 32;
        float ap = ap_l[s_], an = an_l[s_];
        float m = -1e30f;
        #pragma unroll 8
        for (int g = 0; g < 32; ++g) {
            float2 wv = wpn[g0 + g];
            m = fmaxf(m, fmaf(wv.x, ap, wv.y * an));
        }
        mx2[gh][s_] = m;
        __syncthreads();
        m = fmaxf(mx2[0][s_], mx2[1][s_]);
        float d = 0.f;
        #pragma unroll 8
        for (int g = 0; g < 32; ++g) {
            float2 wv = wpn[g0 + g];
            d += __expf(fmaf(wv.x, ap, wv.y * an) - m);
        }
        dn2[gh][s_] = d;
        __syncthreads();
        float inv = 1.0f / (dn2[0][s_] + dn2[1][s_]);
        #pragma unroll 8
        for (int g = 0; g < 32; ++g) {
            float2 wv = wpn[g0 + g];
            sb[g0 + g][s_] = f2bf(__expf(fmaf(wv.x, ap, wv.y * an) - m) * inv);
        }
    }
    __syncthreads();

    // ---- phase C: MFMA, wave owns e-tile [16w, 16w+16) ----
    floatx4 acc[4] = {{0.f,0.f,0.f,0.f},{0.f,0.f,0.f,0.f},
                      {0.f,0.f,0.f,0.f},{0.f,0.f,0.f,0.f}};
    #pragma unroll
    for (int ks = 0; ks < 4; ++ks) {
        short8 av;
        #pragma unroll
        for (int j = 0; j < 8; ++j) av[j] = f2bf(vreg[ks * 8 + j]);
        #pragma unroll
        for (int n = 0; n < 4; ++n) {
            short8 bv = *(const short8*)&sb[16 * n + c][ks * 32 + sq * 8];
            acc[n] = __builtin_amdgcn_mfma_f32_16x16x32_bf16(av, bv, acc[n], 0, 0, 0);
        }
    }

    // epilogue: plain stores into partial[chunk][out_flat],
    // out_flat = ((b*64+e)*8+h)*64+g, e=16w+sq*4+r, g=16n+c.
    float* pch = partial + (size_t)chunk * (NB * NE * NH * NG);
    #pragma unroll
    for (int n = 0; n < 4; ++n) {
        #pragma unroll
        for (int r = 0; r < 4; ++r) {
            int e = 16 * w + sq * 4 + r;
            int g = 16 * n + c;
            pch[((size_t)(b * NE + e) * NH + h) * NG + g] = acc[n][r];
        }
    }
}

// Sum the 8 chunk-partials -> out. Fully coalesced float4.
__global__ __launch_bounds__(256) void k_reduce(
    const float* __restrict__ partial, float* __restrict__ out)
{
    int i = blockIdx.x * 256 + threadIdx.x;     // float4 index, 131072 total
    const float4* p = (const float4*)partial;
    float4 s = p[i];
    #pragma unroll
    for (int ch = 1; ch < 8; ++ch) {
        float4 t = p[(size_t)ch * 131072 + i];
        s.x += t.x; s.y += t.y; s.z += t.z; s.w += t.w;
    }
    ((float4*)out)[i] = s;
}

extern "C" void kernel_launch(void* const* d_in, const int* in_sizes, int n_in,
                              void* d_out, int out_size, void* d_ws, size_t ws_size,
                              hipStream_t stream) {
    (void)in_sizes; (void)n_in; (void)ws_size; (void)out_size;
    const float* queries = (const float*)d_in[0];
    const float* keys    = (const float*)d_in[1];
    const float* values  = (const float*)d_in[2];
    const float* x       = (const float*)d_in[3];
    const float* mlp_w   = (const float*)d_in[4];
    const float* mlp_b   = (const float*)d_in[5];
    const float* sel_W   = (const float*)d_in[6];
    float* out = (float*)d_out;

    // ws layout (floats): partial[8 * 524288] | qp[8192] | qn[8192]
    float* partial = (float*)d_ws;
    float* qp_ws = partial + 8 * (NB * NE * NH * NG);
    float* qn_ws = qp_ws + NB * NH * NE;

    hipMemsetAsync(qp_ws, 0, (size_t)2 * NB * NH * NE * sizeof(float), stream);

    k_sel_q<<<dim3(NB * NH * 8), dim3(256), 0, stream>>>(x, mlp_w, mlp_b,
                                                          queries, qp_ws, qn_ws);
    k_attn_out<<<dim3(NB * NH * 8), dim3(256), 0, stream>>>(keys, values, sel_W,
                                                            qp_ws, qn_ws, partial);
    k_reduce<<<dim3(512), dim3(256), 0, stream>>>(partial, out);
}

// Round 6
// 201.888 us; speedup vs baseline: 1.0042x; 1.0042x over previous
//
#include <hip/hip_runtime.h>
#include <math.h>

#define NB 16
#define NL 1024
#define NH 8
#define NE 64
#define NWIN 1024
#define NG 64

#define SCH 64      // s-chunk per block in k_attn_out
#define SROW 72     // sb row stride in shorts (72*2=144 B, 16B-aligned)
#define NCH 16      // s-chunks per (b,h)

typedef __attribute__((ext_vector_type(8))) short short8;
typedef __attribute__((ext_vector_type(4))) float floatx4;

__device__ __forceinline__ short f2bf(float x) {
    unsigned u = __float_as_uint(x);
    u += 0x7fffu + ((u >> 16) & 1u);   // round-to-nearest-even
    return (short)(u >> 16);
}
__device__ __forceinline__ float dot4(float4 a, float4 b) {
    return fmaf(a.x, b.x, fmaf(a.y, b.y, fmaf(a.z, b.z, a.w * b.w)));
}

// Fused tanh-MLP + qp/qn, v3. Block = (b, h, oct of 16 l8-rows), 1024 blocks.
// Wave w owns k-quarter [w*256, w*256+256); its mlp_w slice lives in 32 VGPRs
// (no 32KB LDS w-tile -> occupancy up). Per row: 8 dot4 + depth-3 merge
// (7 shfl) -> LDS scratch (permuted index, 2-way/free banks); one final
// 128-thread pass does the 32-term sums + ONE batched tanh (replaces 16
// serial 6-deep shuffle+tanh tails).
__global__ __launch_bounds__(256, 5) void k_sel_q(
    const float* __restrict__ x, const float* __restrict__ mlp_w,
    const float* __restrict__ mlp_b, const float* __restrict__ q,
    float* __restrict__ qp, float* __restrict__ qn)
{
    __shared__ float red[4][16][64];   // [kquad][row][c*8+g]  16 KB
    __shared__ float t_lds[128];
    __shared__ float redp[4][64], redn[4][64];

    int tid = threadIdx.x, blk = blockIdx.x;
    int oct = blk & 7, bh = blk >> 3;
    int b = bh >> 3, h = bh & 7;
    int w = tid >> 6, lane = tid & 63;

    // mlp_w k-slice in regs: w4[c] = mlp_w[c][w*256 + lane*4 .. +4)
    float4 w4[8];
    const float* wq = mlp_w + w * 256 + lane * 4;
    #pragma unroll
    for (int c = 0; c < 8; ++c)
        w4[c] = *(const float4*)(wq + (size_t)c * NWIN);

    int r0 = b * 1024 + h * 128 + oct * 16;
    const float* xbase = x + (size_t)r0 * NWIN + w * 256 + lane * 4;

    #pragma unroll
    for (int batch = 0; batch < 2; ++batch) {
        float4 xv[8];
        #pragma unroll
        for (int j = 0; j < 8; ++j)
            xv[j] = *(const float4*)(xbase + (size_t)(batch * 8 + j) * NWIN);
        #pragma unroll
        for (int j = 0; j < 8; ++j) {
            float o0 = dot4(xv[j], w4[0]), o1 = dot4(xv[j], w4[1]);
            float o2 = dot4(xv[j], w4[2]), o3 = dot4(xv[j], w4[3]);
            float o4 = dot4(xv[j], w4[4]), o5 = dot4(xv[j], w4[5]);
            float o6 = dot4(xv[j], w4[6]), o7 = dot4(xv[j], w4[7]);
            // depth-3 merge: lane ends with output c=lane&7, partial over its
            // group of 8 lanes (g = lane>>3)
            o0 += __shfl_xor(o0, 1, 64); o1 += __shfl_xor(o1, 1, 64);
            o2 += __shfl_xor(o2, 1, 64); o3 += __shfl_xor(o3, 1, 64);
            o4 += __shfl_xor(o4, 1, 64); o5 += __shfl_xor(o5, 1, 64);
            o6 += __shfl_xor(o6, 1, 64); o7 += __shfl_xor(o7, 1, 64);
            bool b0 = lane & 1;
            float m0 = b0 ? o1 : o0, m1 = b0 ? o3 : o2;
            float m2 = b0 ? o5 : o4, m3 = b0 ? o7 : o6;
            m0 += __shfl_xor(m0, 2, 64); m1 += __shfl_xor(m1, 2, 64);
            m2 += __shfl_xor(m2, 2, 64); m3 += __shfl_xor(m3, 2, 64);
            bool b1 = lane & 2;
            float n0 = b1 ? m1 : m0, n1 = b1 ? m3 : m2;
            n0 += __shfl_xor(n0, 4, 64); n1 += __shfl_xor(n1, 4, 64);
            float f = (lane & 4) ? n1 : n0;
            red[w][batch * 8 + j][(lane & 7) * 8 + (lane >> 3)] = f;
        }
    }
    __syncthreads();

    // final: output (row j, c) = sum over 4 kquads x 8 groups (+bias, tanh)
    if (tid < 128) {
        int j = tid >> 3, c = tid & 7;
        float s = 0.f;
        #pragma unroll
        for (int w2 = 0; w2 < 4; ++w2) {
            float4 a = *(const float4*)&red[w2][j][c * 8];
            float4 d = *(const float4*)&red[w2][j][c * 8 + 4];
            s += a.x + a.y + a.z + a.w + d.x + d.y + d.z + d.w;
        }
        t_lds[tid] = tanhf(s + mlp_b[c]);   // l_loc = j*8+c = tid
    }
    __syncthreads();

    // phase 2: qp/qn partial over l in [oct*128, oct*128+128)
    int lo = lane >> 4, e4 = lane & 15;
    float4 accp = make_float4(0,0,0,0), accn = make_float4(0,0,0,0);
    #pragma unroll
    for (int i = 0; i < 8; ++i) {
        int l_loc = w * 32 + i * 4 + lo;
        float tv = t_lds[l_loc];
        int l = oct * 128 + l_loc;
        float4 qv = *(const float4*)(q + (((size_t)(b * NL + l)) * NH + h) * NE + e4 * 4);
        float tp = fmaxf(tv, 0.f), tn = fminf(tv, 0.f);
        accp.x = fmaf(tp, qv.x, accp.x); accp.y = fmaf(tp, qv.y, accp.y);
        accp.z = fmaf(tp, qv.z, accp.z); accp.w = fmaf(tp, qv.w, accp.w);
        accn.x = fmaf(tn, qv.x, accn.x); accn.y = fmaf(tn, qv.y, accn.y);
        accn.z = fmaf(tn, qv.z, accn.z); accn.w = fmaf(tn, qv.w, accn.w);
    }
    #pragma unroll
    for (int off = 16; off <= 32; off <<= 1) {
        accp.x += __shfl_xor(accp.x, off, 64); accp.y += __shfl_xor(accp.y, off, 64);
        accp.z += __shfl_xor(accp.z, off, 64); accp.w += __shfl_xor(accp.w, off, 64);
        accn.x += __shfl_xor(accn.x, off, 64); accn.y += __shfl_xor(accn.y, off, 64);
        accn.z += __shfl_xor(accn.z, off, 64); accn.w += __shfl_xor(accn.w, off, 64);
    }
    if (lo == 0) {
        *(float4*)&redp[w][e4 * 4] = accp;
        *(float4*)&redn[w][e4 * 4] = accn;
    }
    __syncthreads();
    if (tid < 64) {
        atomicAdd(&qp[bh * NE + tid], redp[0][tid] + redp[1][tid] + redp[2][tid] + redp[3][tid]);
    } else if (tid < 128) {
        int e = tid - 64;
        atomicAdd(&qn[bh * NE + e], redn[0][e] + redn[1][e] + redn[2][e] + redn[3][e]);
    }
}

// Attention v6: per (b, h, s-chunk of 64), grid 2048 -> 8 blocks/CU
// (wave-slot cap). v loaded AND packed to bf16 up-front (8 VGPRs live;
// sched_barrier stops the scheduler sinking the loads — round-5's VGPR=36
// proved the f32 prefetch was being undone). Epilogue: plain stores to
// per-chunk partials.
__global__ __launch_bounds__(256, 8) void k_attn_out(
    const float* __restrict__ keys, const float* __restrict__ values,
    const float* __restrict__ sel_W,
    const float* __restrict__ qp, const float* __restrict__ qn,
    float* __restrict__ partial)
{
    __shared__ short sb[NG][SROW];          // 9.2 KB  series bf16 [g][s]
    __shared__ float ap_l[SCH], an_l[SCH];
    __shared__ float2 wpn[NG];
    __shared__ float mx4[4][SCH], dn4[4][SCH];

    int tid = threadIdx.x, blk = blockIdx.x;
    int chunk = blk & (NCH - 1), bh = blk >> 4;
    int b = bh >> 3, h = bh & 7;
    int w = tid >> 6, lane = tid & 63;
    int c = lane & 15, sq = lane >> 4;
    const float scale = 0.125f;             // 1/sqrt(64)
    int s0 = chunk * SCH;

    // ---- v prefetch + immediate bf16 pack (A-frags for phase C) ----
    short8 av[2];
    const float* vbase = values + (((size_t)(b * NL + s0)) * NH + h) * NE + 16 * w + c;
    #pragma unroll
    for (int ks = 0; ks < 2; ++ks) {
        float tmp[8];
        #pragma unroll
        for (int j = 0; j < 8; ++j)
            tmp[j] = vbase[(size_t)(ks * 32 + sq * 8 + j) * (NH * NE)];
        #pragma unroll
        for (int j = 0; j < 8; ++j) av[ks][j] = f2bf(tmp[j]);
    }
    __builtin_amdgcn_sched_barrier(0);

    if (tid < NG) {
        float W = sel_W[h * NG + tid];
        wpn[tid] = make_float2(fmaxf(W, 0.f) * scale, fminf(W, 0.f) * scale);
    }
    const float4 qp4 = *(const float4*)(qp + bh * NE + c * 4);
    const float4 qn4 = *(const float4*)(qn + bh * NE + c * 4);

    // ---- phase A: ap/an (wave owns 16 s) ----
    #pragma unroll
    for (int p = 0; p < 4; ++p) {
        int sl = w * 16 + p * 4 + sq;
        float4 kv = *(const float4*)(keys + (((size_t)(b * NL + s0 + sl)) * NH + h) * NE + c * 4);
        float pp = dot4(kv, qp4);
        float pn = dot4(kv, qn4);
        #pragma unroll
        for (int m_ = 1; m_ <= 8; m_ <<= 1) {
            pp += __shfl_xor(pp, m_, 64);
            pn += __shfl_xor(pn, m_, 64);
        }
        if (c == 0) { ap_l[sl] = pp; an_l[sl] = pn; }
    }
    __syncthreads();

    // ---- phase B: softmax over g, g-range split 4-way across thread quads ----
    {
        int s_ = tid & 63, q4 = tid >> 6, g0 = q4 * 16;
        float ap = ap_l[s_], an = an_l[s_];
        float m = -1e30f;
        #pragma unroll
        for (int g = 0; g < 16; ++g) {
            float2 wv = wpn[g0 + g];
            m = fmaxf(m, fmaf(wv.x, ap, wv.y * an));
        }
        mx4[q4][s_] = m;
        __syncthreads();
        m = fmaxf(fmaxf(mx4[0][s_], mx4[1][s_]), fmaxf(mx4[2][s_], mx4[3][s_]));
        float d = 0.f;
        #pragma unroll
        for (int g = 0; g < 16; ++g) {
            float2 wv = wpn[g0 + g];
            d += __expf(fmaf(wv.x, ap, wv.y * an) - m);
        }
        dn4[q4][s_] = d;
        __syncthreads();
        float inv = 1.0f / (dn4[0][s_] + dn4[1][s_] + dn4[2][s_] + dn4[3][s_]);
        #pragma unroll
        for (int g = 0; g < 16; ++g) {
            float2 wv = wpn[g0 + g];
            sb[g0 + g][s_] = f2bf(__expf(fmaf(wv.x, ap, wv.y * an) - m) * inv);
        }
    }
    __syncthreads();

    // ---- phase C: MFMA, wave owns e-tile [16w, 16w+16) ----
    floatx4 acc[4] = {{0.f,0.f,0.f,0.f},{0.f,0.f,0.f,0.f},
                      {0.f,0.f,0.f,0.f},{0.f,0.f,0.f,0.f}};
    #pragma unroll
    for (int ks = 0; ks < 2; ++ks) {
        #pragma unroll
        for (int n = 0; n < 4; ++n) {
            short8 bv = *(const short8*)&sb[16 * n + c][ks * 32 + sq * 8];
            acc[n] = __builtin_amdgcn_mfma_f32_16x16x32_bf16(av[ks], bv, acc[n], 0, 0, 0);
        }
    }

    // epilogue: partial[chunk][out_flat], out_flat = ((b*64+e)*8+h)*64+g
    float* pch = partial + (size_t)chunk * (NB * NE * NH * NG);
    #pragma unroll
    for (int n = 0; n < 4; ++n) {
        #pragma unroll
        for (int r = 0; r < 4; ++r) {
            int e = 16 * w + sq * 4 + r;
            int g = 16 * n + c;
            pch[((size_t)(b * NE + e) * NH + h) * NG + g] = acc[n][r];
        }
    }
}

// Sum the 16 chunk-partials -> out. Fully coalesced float4.
__global__ __launch_bounds__(256) void k_reduce(
    const float* __restrict__ partial, float* __restrict__ out)
{
    int i = blockIdx.x * 256 + threadIdx.x;     // float4 index, 131072 total
    const float4* p = (const float4*)partial;
    float4 s = p[i];
    #pragma unroll
    for (int ch = 1; ch < NCH; ++ch) {
        float4 t = p[(size_t)ch * 131072 + i];
        s.x += t.x; s.y += t.y; s.z += t.z; s.w += t.w;
    }
    ((float4*)out)[i] = s;
}

extern "C" void kernel_launch(void* const* d_in, const int* in_sizes, int n_in,
                              void* d_out, int out_size, void* d_ws, size_t ws_size,
                              hipStream_t stream) {
    (void)in_sizes; (void)n_in; (void)ws_size; (void)out_size;
    const float* queries = (const float*)d_in[0];
    const float* keys    = (const float*)d_in[1];
    const float* values  = (const float*)d_in[2];
    const float* x       = (const float*)d_in[3];
    const float* mlp_w   = (const float*)d_in[4];
    const float* mlp_b   = (const float*)d_in[5];
    const float* sel_W   = (const float*)d_in[6];
    float* out = (float*)d_out;

    // ws layout (floats): partial[16 * 524288] | qp[8192] | qn[8192]
    float* partial = (float*)d_ws;
    float* qp_ws = partial + (size_t)NCH * (NB * NE * NH * NG);
    float* qn_ws = qp_ws + NB * NH * NE;

    hipMemsetAsync(qp_ws, 0, (size_t)2 * NB * NH * NE * sizeof(float), stream);

    k_sel_q<<<dim3(NB * NH * 8), dim3(256), 0, stream>>>(x, mlp_w, mlp_b,
                                                          queries, qp_ws, qn_ws);
    k_attn_out<<<dim3(NB * NH * NCH), dim3(256), 0, stream>>>(keys, values, sel_W,
                                                              qp_ws, qn_ws, partial);
    k_reduce<<<dim3(512), dim3(256), 0, stream>>>(partial, out);
}

// Round 7
// 201.740 us; speedup vs baseline: 1.0049x; 1.0007x over previous
//
#include <hip/hip_runtime.h>
#include <math.h>

#define NB 16
#define NL 1024
#define NH 8
#define NE 64
#define NWIN 1024
#define NG 64

#define SCH 64      // s-chunk per block in k_attn_out
#define SROW 72     // sb row stride in shorts (72*2=144 B, 16B-aligned)
#define NCH 16      // s-chunks per (b,h)

typedef __attribute__((ext_vector_type(8))) short short8;
typedef __attribute__((ext_vector_type(4))) float floatx4;

__device__ __forceinline__ short f2bf(float x) {
    unsigned u = __float_as_uint(x);
    u += 0x7fffu + ((u >> 16) & 1u);   // round-to-nearest-even
    return (short)(u >> 16);
}
__device__ __forceinline__ float dot4(float4 a, float4 b) {
    return fmaf(a.x, b.x, fmaf(a.y, b.y, fmaf(a.z, b.z, a.w * b.w)));
}

// Fused tanh-MLP + qp/qn, v4 (MLP-maximizing variant). Block = (b,h,oct).
// ALL global loads for the block issue up-front per lane: 8 w-float4 +
// 16 x-float4 + 8 q-float4 = 32 loads (512 B) in flight per lane. No VGPR
// cap (round-6's (256,5) likely spilled). Compute then runs on registers:
// per row 8 dot4 + depth-3 merge -> LDS; batched tanh; reg-resident q phase.
__global__ __launch_bounds__(256) void k_sel_q(
    const float* __restrict__ x, const float* __restrict__ mlp_w,
    const float* __restrict__ mlp_b, const float* __restrict__ q,
    float* __restrict__ qp, float* __restrict__ qn)
{
    __shared__ float red[4][16][64];   // [kquad][row][c*8+g]  16 KB
    __shared__ float t_lds[128];
    __shared__ float redp[4][64], redn[4][64];

    int tid = threadIdx.x, blk = blockIdx.x;
    int oct = blk & 7, bh = blk >> 3;
    int b = bh >> 3, h = bh & 7;
    int w = tid >> 6, lane = tid & 63;
    int lo = lane >> 4, e4 = lane & 15;

    // ---- prefetch everything ----
    float4 w4[8];
    const float* wq = mlp_w + w * 256 + lane * 4;
    #pragma unroll
    for (int c = 0; c < 8; ++c)
        w4[c] = *(const float4*)(wq + (size_t)c * NWIN);

    int r0 = b * 1024 + h * 128 + oct * 16;
    const float* xbase = x + (size_t)r0 * NWIN + w * 256 + lane * 4;
    float4 xv[16];
    #pragma unroll
    for (int j = 0; j < 16; ++j)
        xv[j] = *(const float4*)(xbase + (size_t)j * NWIN);

    float4 q4[8];
    #pragma unroll
    for (int i = 0; i < 8; ++i) {
        int l = oct * 128 + w * 32 + i * 4 + lo;
        q4[i] = *(const float4*)(q + (((size_t)(b * NL + l)) * NH + h) * NE + e4 * 4);
    }
    __builtin_amdgcn_sched_barrier(0);

    // ---- phase 1: dots + depth-3 merge per row ----
    #pragma unroll
    for (int j = 0; j < 16; ++j) {
        float o0 = dot4(xv[j], w4[0]), o1 = dot4(xv[j], w4[1]);
        float o2 = dot4(xv[j], w4[2]), o3 = dot4(xv[j], w4[3]);
        float o4 = dot4(xv[j], w4[4]), o5 = dot4(xv[j], w4[5]);
        float o6 = dot4(xv[j], w4[6]), o7 = dot4(xv[j], w4[7]);
        o0 += __shfl_xor(o0, 1, 64); o1 += __shfl_xor(o1, 1, 64);
        o2 += __shfl_xor(o2, 1, 64); o3 += __shfl_xor(o3, 1, 64);
        o4 += __shfl_xor(o4, 1, 64); o5 += __shfl_xor(o5, 1, 64);
        o6 += __shfl_xor(o6, 1, 64); o7 += __shfl_xor(o7, 1, 64);
        bool b0 = lane & 1;
        float m0 = b0 ? o1 : o0, m1 = b0 ? o3 : o2;
        float m2 = b0 ? o5 : o4, m3 = b0 ? o7 : o6;
        m0 += __shfl_xor(m0, 2, 64); m1 += __shfl_xor(m1, 2, 64);
        m2 += __shfl_xor(m2, 2, 64); m3 += __shfl_xor(m3, 2, 64);
        bool b1 = lane & 2;
        float n0 = b1 ? m1 : m0, n1 = b1 ? m3 : m2;
        n0 += __shfl_xor(n0, 4, 64); n1 += __shfl_xor(n1, 4, 64);
        float f = (lane & 4) ? n1 : n0;
        red[w][j][(lane & 7) * 8 + (lane >> 3)] = f;
    }
    __syncthreads();

    // ---- batched tanh: output (row j, c) = sum 4 kquads x 8 groups ----
    if (tid < 128) {
        int j = tid >> 3, c = tid & 7;
        float s = 0.f;
        #pragma unroll
        for (int w2 = 0; w2 < 4; ++w2) {
            float4 a = *(const float4*)&red[w2][j][c * 8];
            float4 d = *(const float4*)&red[w2][j][c * 8 + 4];
            s += a.x + a.y + a.z + a.w + d.x + d.y + d.z + d.w;
        }
        t_lds[tid] = tanhf(s + mlp_b[c]);   // l_loc = j*8+c = tid
    }
    __syncthreads();

    // ---- phase 2: qp/qn from register-resident q4 ----
    float4 accp = make_float4(0,0,0,0), accn = make_float4(0,0,0,0);
    #pragma unroll
    for (int i = 0; i < 8; ++i) {
        float tv = t_lds[w * 32 + i * 4 + lo];
        float tp = fmaxf(tv, 0.f), tn = fminf(tv, 0.f);
        accp.x = fmaf(tp, q4[i].x, accp.x); accp.y = fmaf(tp, q4[i].y, accp.y);
        accp.z = fmaf(tp, q4[i].z, accp.z); accp.w = fmaf(tp, q4[i].w, accp.w);
        accn.x = fmaf(tn, q4[i].x, accn.x); accn.y = fmaf(tn, q4[i].y, accn.y);
        accn.z = fmaf(tn, q4[i].z, accn.z); accn.w = fmaf(tn, q4[i].w, accn.w);
    }
    #pragma unroll
    for (int off = 16; off <= 32; off <<= 1) {
        accp.x += __shfl_xor(accp.x, off, 64); accp.y += __shfl_xor(accp.y, off, 64);
        accp.z += __shfl_xor(accp.z, off, 64); accp.w += __shfl_xor(accp.w, off, 64);
        accn.x += __shfl_xor(accn.x, off, 64); accn.y += __shfl_xor(accn.y, off, 64);
        accn.z += __shfl_xor(accn.z, off, 64); accn.w += __shfl_xor(accn.w, off, 64);
    }
    if (lo == 0) {
        *(float4*)&redp[w][e4 * 4] = accp;
        *(float4*)&redn[w][e4 * 4] = accn;
    }
    __syncthreads();
    if (tid < 64) {
        atomicAdd(&qp[bh * NE + tid], redp[0][tid] + redp[1][tid] + redp[2][tid] + redp[3][tid]);
    } else if (tid < 128) {
        int e = tid - 64;
        atomicAdd(&qn[bh * NE + e], redn[0][e] + redn[1][e] + redn[2][e] + redn[3][e]);
    }
}

// Attention v7: per (b, h, s-chunk of 64). ALL global loads prefetched:
// k4[4] (phase A) + v tmp[16] (phase C) issue before anything else and stay
// in registers across the barriers (no VGPR cap so nothing spills/sinks).
__global__ __launch_bounds__(256) void k_attn_out(
    const float* __restrict__ keys, const float* __restrict__ values,
    const float* __restrict__ sel_W,
    const float* __restrict__ qp, const float* __restrict__ qn,
    float* __restrict__ partial)
{
    __shared__ short sb[NG][SROW];          // 9.2 KB  series bf16 [g][s]
    __shared__ float ap_l[SCH], an_l[SCH];
    __shared__ float2 wpn[NG];
    __shared__ float mx4[4][SCH], dn4[4][SCH];

    int tid = threadIdx.x, blk = blockIdx.x;
    int chunk = blk & (NCH - 1), bh = blk >> 4;
    int b = bh >> 3, h = bh & 7;
    int w = tid >> 6, lane = tid & 63;
    int c = lane & 15, sq = lane >> 4;
    const float scale = 0.125f;             // 1/sqrt(64)
    int s0 = chunk * SCH;

    // ---- prefetch: v (16 scalars) + k (4 float4) ----
    float vt[16];
    const float* vbase = values + (((size_t)(b * NL + s0)) * NH + h) * NE + 16 * w + c;
    #pragma unroll
    for (int ks = 0; ks < 2; ++ks)
        #pragma unroll
        for (int j = 0; j < 8; ++j)
            vt[ks * 8 + j] = vbase[(size_t)(ks * 32 + sq * 8 + j) * (NH * NE)];
    float4 k4[4];
    #pragma unroll
    for (int p = 0; p < 4; ++p) {
        int sl = w * 16 + p * 4 + sq;
        k4[p] = *(const float4*)(keys + (((size_t)(b * NL + s0 + sl)) * NH + h) * NE + c * 4);
    }
    __builtin_amdgcn_sched_barrier(0);

    if (tid < NG) {
        float W = sel_W[h * NG + tid];
        wpn[tid] = make_float2(fmaxf(W, 0.f) * scale, fminf(W, 0.f) * scale);
    }
    const float4 qp4 = *(const float4*)(qp + bh * NE + c * 4);
    const float4 qn4 = *(const float4*)(qn + bh * NE + c * 4);

    // ---- phase A: ap/an (wave owns 16 s) ----
    #pragma unroll
    for (int p = 0; p < 4; ++p) {
        int sl = w * 16 + p * 4 + sq;
        float pp = dot4(k4[p], qp4);
        float pn = dot4(k4[p], qn4);
        #pragma unroll
        for (int m_ = 1; m_ <= 8; m_ <<= 1) {
            pp += __shfl_xor(pp, m_, 64);
            pn += __shfl_xor(pn, m_, 64);
        }
        if (c == 0) { ap_l[sl] = pp; an_l[sl] = pn; }
    }
    __syncthreads();

    // ---- phase B: softmax over g, g-range split 4-way ----
    {
        int s_ = tid & 63, q4i = tid >> 6, g0 = q4i * 16;
        float ap = ap_l[s_], an = an_l[s_];
        float m = -1e30f;
        #pragma unroll
        for (int g = 0; g < 16; ++g) {
            float2 wv = wpn[g0 + g];
            m = fmaxf(m, fmaf(wv.x, ap, wv.y * an));
        }
        mx4[q4i][s_] = m;
        __syncthreads();
        m = fmaxf(fmaxf(mx4[0][s_], mx4[1][s_]), fmaxf(mx4[2][s_], mx4[3][s_]));
        float d = 0.f;
        #pragma unroll
        for (int g = 0; g < 16; ++g) {
            float2 wv = wpn[g0 + g];
            d += __expf(fmaf(wv.x, ap, wv.y * an) - m);
        }
        dn4[q4i][s_] = d;
        __syncthreads();
        float inv = 1.0f / (dn4[0][s_] + dn4[1][s_] + dn4[2][s_] + dn4[3][s_]);
        #pragma unroll
        for (int g = 0; g < 16; ++g) {
            float2 wv = wpn[g0 + g];
            sb[g0 + g][s_] = f2bf(__expf(fmaf(wv.x, ap, wv.y * an) - m) * inv);
        }
    }
    __syncthreads();

    // ---- phase C: pack v, MFMA; wave owns e-tile [16w, 16w+16) ----
    floatx4 acc[4] = {{0.f,0.f,0.f,0.f},{0.f,0.f,0.f,0.f},
                      {0.f,0.f,0.f,0.f},{0.f,0.f,0.f,0.f}};
    #pragma unroll
    for (int ks = 0; ks < 2; ++ks) {
        short8 av;
        #pragma unroll
        for (int j = 0; j < 8; ++j) av[j] = f2bf(vt[ks * 8 + j]);
        #pragma unroll
        for (int n = 0; n < 4; ++n) {
            short8 bv = *(const short8*)&sb[16 * n + c][ks * 32 + sq * 8];
            acc[n] = __builtin_amdgcn_mfma_f32_16x16x32_bf16(av, bv, acc[n], 0, 0, 0);
        }
    }

    // epilogue: partial[chunk][out_flat], out_flat = ((b*64+e)*8+h)*64+g
    float* pch = partial + (size_t)chunk * (NB * NE * NH * NG);
    #pragma unroll
    for (int n = 0; n < 4; ++n) {
        #pragma unroll
        for (int r = 0; r < 4; ++r) {
            int e = 16 * w + sq * 4 + r;
            int g = 16 * n + c;
            pch[((size_t)(b * NE + e) * NH + h) * NG + g] = acc[n][r];
        }
    }
}

// Sum the 16 chunk-partials -> out. Fully coalesced float4.
__global__ __launch_bounds__(256) void k_reduce(
    const float* __restrict__ partial, float* __restrict__ out)
{
    int i = blockIdx.x * 256 + threadIdx.x;     // float4 index, 131072 total
    const float4* p = (const float4*)partial;
    float4 s = p[i];
    #pragma unroll
    for (int ch = 1; ch < NCH; ++ch) {
        float4 t = p[(size_t)ch * 131072 + i];
        s.x += t.x; s.y += t.y; s.z += t.z; s.w += t.w;
    }
    ((float4*)out)[i] = s;
}

extern "C" void kernel_launch(void* const* d_in, const int* in_sizes, int n_in,
                              void* d_out, int out_size, void* d_ws, size_t ws_size,
                              hipStream_t stream) {
    (void)in_sizes; (void)n_in; (void)ws_size; (void)out_size;
    const float* queries = (const float*)d_in[0];
    const float* keys    = (const float*)d_in[1];
    const float* values  = (const float*)d_in[2];
    const float* x       = (const float*)d_in[3];
    const float* mlp_w   = (const float*)d_in[4];
    const float* mlp_b   = (const float*)d_in[5];
    const float* sel_W   = (const float*)d_in[6];
    float* out = (float*)d_out;

    // ws layout (floats): partial[16 * 524288] | qp[8192] | qn[8192]
    float* partial = (float*)d_ws;
    float* qp_ws = partial + (size_t)NCH * (NB * NE * NH * NG);
    float* qn_ws = qp_ws + NB * NH * NE;

    hipMemsetAsync(qp_ws, 0, (size_t)2 * NB * NH * NE * sizeof(float), stream);

    k_sel_q<<<dim3(NB * NH * 8), dim3(256), 0, stream>>>(x, mlp_w, mlp_b,
                                                          queries, qp_ws, qn_ws);
    k_attn_out<<<dim3(NB * NH * NCH), dim3(256), 0, stream>>>(keys, values, sel_W,
                                                              qp_ws, qn_ws, partial);
    k_reduce<<<dim3(512), dim3(256), 0, stream>>>(partial, out);
}

// Round 8
// 201.337 us; speedup vs baseline: 1.0069x; 1.0020x over previous
//
#include <hip/hip_runtime.h>
#include <math.h>

#define NB 16
#define NL 1024
#define NH 8
#define NE 64
#define NWIN 1024
#define NG 64

#define SCH 64      // s-chunk per block in k_attn_out
#define SROW 72     // sb row stride in shorts (72*2=144 B, 16B-aligned)
#define NCH 16      // s-chunks per (b,h)

typedef __attribute__((ext_vector_type(8))) short short8;
typedef __attribute__((ext_vector_type(4))) float floatx4;

__device__ __forceinline__ short f2bf(float x) {
    unsigned u = __float_as_uint(x);
    u += 0x7fffu + ((u >> 16) & 1u);   // round-to-nearest-even
    return (short)(u >> 16);
}
__device__ __forceinline__ float dot4(float4 a, float4 b) {
    return fmaf(a.x, b.x, fmaf(a.y, b.y, fmaf(a.z, b.z, a.w * b.w)));
}

// Fused tanh-MLP + qp/qn — round-5 proven body (41 µs, 0 conflicts), with ONE
// change: h in the LOW bits of blockIdx. The q reads touch 256 B of every
// 2 KB (h-stride); putting all 8 h of the same l-range in adjacent blocks
// makes their complementary DRAM-page slices arrive together (page-hit test).
__global__ __launch_bounds__(256) void k_sel_q(
    const float* __restrict__ x, const float* __restrict__ mlp_w,
    const float* __restrict__ mlp_b, const float* __restrict__ q,
    float* __restrict__ qp, float* __restrict__ qn)
{
    __shared__ float4 w_lds[8][NWIN / 4];   // 32 KB
    __shared__ float t_lds[128];
    __shared__ float redp[4][64], redn[4][64];

    int tid = threadIdx.x;
    int blk = blockIdx.x;
    // blk = ((b*8 + oct)*8) + h  -> h adjacent
    int h = blk & 7;
    int qq = (blk >> 3) & 7;
    int b = blk >> 6;
    int bh = b * 8 + h;
    int w = tid >> 6, lane = tid & 63;

    const float4* w4 = (const float4*)mlp_w;
    float4* wl = (float4*)w_lds;
    #pragma unroll
    for (int i = 0; i < 8; ++i)
        wl[tid + 256 * i] = w4[tid + 256 * i];
    __syncthreads();

    // ---- phase 1: tanh-MLP, 4 rows per wave, double-buffered x ----
    int r0 = b * 1024 + h * 128 + qq * 16 + w * 4;
    float bc = mlp_b[lane & 7];
    float4 xa[4], xb[4];
    {
        const float4* p0 = (const float4*)(x + (size_t)r0 * NWIN);
        #pragma unroll
        for (int it = 0; it < 4; ++it) xa[it] = p0[it * 64 + lane];
    }
    #pragma unroll
    for (int j = 0; j < 4; ++j) {
        if (j < 3) {
            const float4* pn = (const float4*)(x + (size_t)(r0 + j + 1) * NWIN);
            #pragma unroll
            for (int it = 0; it < 4; ++it) xb[it] = pn[it * 64 + lane];
        }
        float o0=0,o1=0,o2=0,o3=0,o4=0,o5=0,o6=0,o7=0;
        #pragma unroll
        for (int it = 0; it < 4; ++it) {
            float4 xv = xa[it];
            o0 += dot4(xv, w_lds[0][it * 64 + lane]);
            o1 += dot4(xv, w_lds[1][it * 64 + lane]);
            o2 += dot4(xv, w_lds[2][it * 64 + lane]);
            o3 += dot4(xv, w_lds[3][it * 64 + lane]);
            o4 += dot4(xv, w_lds[4][it * 64 + lane]);
            o5 += dot4(xv, w_lds[5][it * 64 + lane]);
            o6 += dot4(xv, w_lds[6][it * 64 + lane]);
            o7 += dot4(xv, w_lds[7][it * 64 + lane]);
        }
        // merge-tree reduction: lane ends with full sum of output c=lane&7
        o0 += __shfl_xor(o0, 1, 64); o1 += __shfl_xor(o1, 1, 64);
        o2 += __shfl_xor(o2, 1, 64); o3 += __shfl_xor(o3, 1, 64);
        o4 += __shfl_xor(o4, 1, 64); o5 += __shfl_xor(o5, 1, 64);
        o6 += __shfl_xor(o6, 1, 64); o7 += __shfl_xor(o7, 1, 64);
        bool b0 = lane & 1;
        float m0 = b0 ? o1 : o0, m1 = b0 ? o3 : o2;
        float m2 = b0 ? o5 : o4, m3 = b0 ? o7 : o6;
        m0 += __shfl_xor(m0, 2, 64); m1 += __shfl_xor(m1, 2, 64);
        m2 += __shfl_xor(m2, 2, 64); m3 += __shfl_xor(m3, 2, 64);
        bool b1 = lane & 2;
        float n0 = b1 ? m1 : m0, n1 = b1 ? m3 : m2;
        n0 += __shfl_xor(n0, 4, 64); n1 += __shfl_xor(n1, 4, 64);
        float q0 = (lane & 4) ? n1 : n0;
        q0 += __shfl_xor(q0, 8, 64);
        q0 += __shfl_xor(q0, 16, 64);
        q0 += __shfl_xor(q0, 32, 64);
        if (lane < 8)
            t_lds[w * 32 + j * 8 + lane] = tanhf(q0 + bc);
        #pragma unroll
        for (int it = 0; it < 4; ++it) xa[it] = xb[it];
    }
    // no barrier: wave w only reads t_lds[w*32 .. w*32+32)

    // ---- phase 2: qp/qn partial over l in [qq*128, qq*128+128) ----
    int lo = lane >> 4, e4 = lane & 15;
    float4 accp = make_float4(0,0,0,0), accn = make_float4(0,0,0,0);
    #pragma unroll
    for (int i = 0; i < 8; ++i) {
        int l_loc = w * 32 + i * 4 + lo;
        float tv = t_lds[l_loc];
        int l = qq * 128 + l_loc;
        float4 qv = *(const float4*)(q + (((size_t)(b * NL + l)) * NH + h) * NE + e4 * 4);
        float tp = fmaxf(tv, 0.f), tn = fminf(tv, 0.f);
        accp.x = fmaf(tp, qv.x, accp.x); accp.y = fmaf(tp, qv.y, accp.y);
        accp.z = fmaf(tp, qv.z, accp.z); accp.w = fmaf(tp, qv.w, accp.w);
        accn.x = fmaf(tn, qv.x, accn.x); accn.y = fmaf(tn, qv.y, accn.y);
        accn.z = fmaf(tn, qv.z, accn.z); accn.w = fmaf(tn, qv.w, accn.w);
    }
    #pragma unroll
    for (int off = 16; off <= 32; off <<= 1) {
        accp.x += __shfl_xor(accp.x, off, 64); accp.y += __shfl_xor(accp.y, off, 64);
        accp.z += __shfl_xor(accp.z, off, 64); accp.w += __shfl_xor(accp.w, off, 64);
        accn.x += __shfl_xor(accn.x, off, 64); accn.y += __shfl_xor(accn.y, off, 64);
        accn.z += __shfl_xor(accn.z, off, 64); accn.w += __shfl_xor(accn.w, off, 64);
    }
    if (lo == 0) {
        *(float4*)&redp[w][e4 * 4] = accp;
        *(float4*)&redn[w][e4 * 4] = accn;
    }
    __syncthreads();
    if (tid < 64) {
        atomicAdd(&qp[bh * NE + tid], redp[0][tid] + redp[1][tid] + redp[2][tid] + redp[3][tid]);
    } else if (tid < 128) {
        int e = tid - 64;
        atomicAdd(&qn[bh * NE + e], redn[0][e] + redn[1][e] + redn[2][e] + redn[3][e]);
    }
}

// Attention v8 = round-7 body with h in the LOW bits of blockIdx (the 8 h
// of one (b,chunk) are dispatch-adjacent -> complementary 256B slices of the
// same k/v DRAM pages arrive together).
__global__ __launch_bounds__(256) void k_attn_out(
    const float* __restrict__ keys, const float* __restrict__ values,
    const float* __restrict__ sel_W,
    const float* __restrict__ qp, const float* __restrict__ qn,
    float* __restrict__ partial)
{
    __shared__ short sb[NG][SROW];          // 9.2 KB  series bf16 [g][s]
    __shared__ float ap_l[SCH], an_l[SCH];
    __shared__ float2 wpn[NG];
    __shared__ float mx4[4][SCH], dn4[4][SCH];

    int tid = threadIdx.x, blk = blockIdx.x;
    // blk = ((b*NCH + chunk)*8) + h -> h adjacent
    int h = blk & 7;
    int chunk = (blk >> 3) & (NCH - 1);
    int b = blk >> 7;
    int bh = b * 8 + h;
    int w = tid >> 6, lane = tid & 63;
    int c = lane & 15, sq = lane >> 4;
    const float scale = 0.125f;             // 1/sqrt(64)
    int s0 = chunk * SCH;

    // ---- prefetch: v (16 scalars) + k (4 float4) ----
    float vt[16];
    const float* vbase = values + (((size_t)(b * NL + s0)) * NH + h) * NE + 16 * w + c;
    #pragma unroll
    for (int ks = 0; ks < 2; ++ks)
        #pragma unroll
        for (int j = 0; j < 8; ++j)
            vt[ks * 8 + j] = vbase[(size_t)(ks * 32 + sq * 8 + j) * (NH * NE)];
    float4 k4[4];
    #pragma unroll
    for (int p = 0; p < 4; ++p) {
        int sl = w * 16 + p * 4 + sq;
        k4[p] = *(const float4*)(keys + (((size_t)(b * NL + s0 + sl)) * NH + h) * NE + c * 4);
    }
    __builtin_amdgcn_sched_barrier(0);

    if (tid < NG) {
        float W = sel_W[h * NG + tid];
        wpn[tid] = make_float2(fmaxf(W, 0.f) * scale, fminf(W, 0.f) * scale);
    }
    const float4 qp4 = *(const float4*)(qp + bh * NE + c * 4);
    const float4 qn4 = *(const float4*)(qn + bh * NE + c * 4);

    // ---- phase A: ap/an (wave owns 16 s) ----
    #pragma unroll
    for (int p = 0; p < 4; ++p) {
        int sl = w * 16 + p * 4 + sq;
        float pp = dot4(k4[p], qp4);
        float pn = dot4(k4[p], qn4);
        #pragma unroll
        for (int m_ = 1; m_ <= 8; m_ <<= 1) {
            pp += __shfl_xor(pp, m_, 64);
            pn += __shfl_xor(pn, m_, 64);
        }
        if (c == 0) { ap_l[sl] = pp; an_l[sl] = pn; }
    }
    __syncthreads();

    // ---- phase B: softmax over g, g-range split 4-way ----
    {
        int s_ = tid & 63, q4i = tid >> 6, g0 = q4i * 16;
        float ap = ap_l[s_], an = an_l[s_];
        float m = -1e30f;
        #pragma unroll
        for (int g = 0; g < 16; ++g) {
            float2 wv = wpn[g0 + g];
            m = fmaxf(m, fmaf(wv.x, ap, wv.y * an));
        }
        mx4[q4i][s_] = m;
        __syncthreads();
        m = fmaxf(fmaxf(mx4[0][s_], mx4[1][s_]), fmaxf(mx4[2][s_], mx4[3][s_]));
        float d = 0.f;
        #pragma unroll
        for (int g = 0; g < 16; ++g) {
            float2 wv = wpn[g0 + g];
            d += __expf(fmaf(wv.x, ap, wv.y * an) - m);
        }
        dn4[q4i][s_] = d;
        __syncthreads();
        float inv = 1.0f / (dn4[0][s_] + dn4[1][s_] + dn4[2][s_] + dn4[3][s_]);
        #pragma unroll
        for (int g = 0; g < 16; ++g) {
            float2 wv = wpn[g0 + g];
            sb[g0 + g][s_] = f2bf(__expf(fmaf(wv.x, ap, wv.y * an) - m) * inv);
        }
    }
    __syncthreads();

    // ---- phase C: pack v, MFMA; wave owns e-tile [16w, 16w+16) ----
    floatx4 acc[4] = {{0.f,0.f,0.f,0.f},{0.f,0.f,0.f,0.f},
                      {0.f,0.f,0.f,0.f},{0.f,0.f,0.f,0.f}};
    #pragma unroll
    for (int ks = 0; ks < 2; ++ks) {
        short8 av;
        #pragma unroll
        for (int j = 0; j < 8; ++j) av[j] = f2bf(vt[ks * 8 + j]);
        #pragma unroll
        for (int n = 0; n < 4; ++n) {
            short8 bv = *(const short8*)&sb[16 * n + c][ks * 32 + sq * 8];
            acc[n] = __builtin_amdgcn_mfma_f32_16x16x32_bf16(av, bv, acc[n], 0, 0, 0);
        }
    }

    // epilogue: partial[chunk][out_flat], out_flat = ((b*64+e)*8+h)*64+g
    float* pch = partial + (size_t)chunk * (NB * NE * NH * NG);
    #pragma unroll
    for (int n = 0; n < 4; ++n) {
        #pragma unroll
        for (int r = 0; r < 4; ++r) {
            int e = 16 * w + sq * 4 + r;
            int g = 16 * n + c;
            pch[((size_t)(b * NE + e) * NH + h) * NG + g] = acc[n][r];
        }
    }
}

// Sum the 16 chunk-partials -> out. Fully coalesced float4.
__global__ __launch_bounds__(256) void k_reduce(
    const float* __restrict__ partial, float* __restrict__ out)
{
    int i = blockIdx.x * 256 + threadIdx.x;     // float4 index, 131072 total
    const float4* p = (const float4*)partial;
    float4 s = p[i];
    #pragma unroll
    for (int ch = 1; ch < NCH; ++ch) {
        float4 t = p[(size_t)ch * 131072 + i];
        s.x += t.x; s.y += t.y; s.z += t.z; s.w += t.w;
    }
    ((float4*)out)[i] = s;
}

extern "C" void kernel_launch(void* const* d_in, const int* in_sizes, int n_in,
                              void* d_out, int out_size, void* d_ws, size_t ws_size,
                              hipStream_t stream) {
    (void)in_sizes; (void)n_in; (void)ws_size; (void)out_size;
    const float* queries = (const float*)d_in[0];
    const float* keys    = (const float*)d_in[1];
    const float* values  = (const float*)d_in[2];
    const float* x       = (const float*)d_in[3];
    const float* mlp_w   = (const float*)d_in[4];
    const float* mlp_b   = (const float*)d_in[5];
    const float* sel_W   = (const float*)d_in[6];
    float* out = (float*)d_out;

    // ws layout (floats): partial[16 * 524288] | qp[8192] | qn[8192]
    float* partial = (float*)d_ws;
    float* qp_ws = partial + (size_t)NCH * (NB * NE * NH * NG);
    float* qn_ws = qp_ws + NB * NH * NE;

    hipMemsetAsync(qp_ws, 0, (size_t)2 * NB * NH * NE * sizeof(float), stream);

    k_sel_q<<<dim3(NB * NH * 8), dim3(256), 0, stream>>>(x, mlp_w, mlp_b,
                                                          queries, qp_ws, qn_ws);
    k_attn_out<<<dim3(NB * NH * NCH), dim3(256), 0, stream>>>(keys, values, sel_W,
                                                              qp_ws, qn_ws, partial);
    k_reduce<<<dim3(512), dim3(256), 0, stream>>>(partial, out);
}